// Round 2
// baseline (223.267 us; speedup 1.0000x reference)
//
#include <hip/hip_runtime.h>

// LIF recurrence over last (time) dim, T=8, fp32 in/out. 4,194,304 neurons.
//   u_t = TAU * u_{t-1} * (1 - o_{t-1}) + x_t ;  o_t = (u_t > VTH) ? 1 : 0
//
// Memory-bound: 134 MB read + 134 MB write -> ~43 us floor at ~6.3 TB/s.
// Unit-stride float4 load/store per lane; a neuron's two time-halves live in
// adjacent lanes (pair 2n/2n+1 of the same wave), so the recurrence carry is
// exchanged in-register via __shfl_xor(1) -- no LDS, no barriers.
//   pass 1: all lanes run their 4 steps from (u,o)=(0,0)   (valid for even lanes)
//   xchg  : odd lanes take partner's (u,o) as carry; even lanes take (0,0)
//   pass 2: all lanes re-run their 4 steps with the correct carry and emit spikes
//
// This revision: persistent grid-stride schedule. 2048 blocks (8 wg/CU -> all
// 32 waves/CU resident once, zero block churn), 16 chunks/thread, software
// pipeline with prefetch distance 2: the next two chunks' loads are in flight
// while the current chunk computes and stores. Per-instruction coalescing and
// the lane-pair parity mapping are unchanged (stride = gridDim*BLOCK, even).

#define LIF_TAU 0.25f
#define LIF_VTH 0.3f
#define BLOCK 256
#define ITERS 16   // float4 chunks per thread; grid = n_vec4 / (BLOCK*ITERS)

typedef float v4f __attribute__((ext_vector_type(4)));

__global__ __launch_bounds__(BLOCK) void lif_spike_kernel(
    const float* __restrict__ x, float* __restrict__ out) {
    const v4f* __restrict__ xv = reinterpret_cast<const v4f*>(x);
    v4f* __restrict__ ov = reinterpret_cast<v4f*>(out);

    const size_t stride = (size_t)gridDim.x * BLOCK;        // vec4 units, even
    size_t idx = (size_t)blockIdx.x * BLOCK + threadIdx.x;

    const bool odd = (threadIdx.x & 1) != 0;

    // prefetch pipeline, depth 2
    v4f cur = __builtin_nontemporal_load(xv + idx);
    v4f nxt = __builtin_nontemporal_load(xv + idx + stride);

#pragma unroll
    for (int k = 0; k < ITERS; ++k) {
        v4f fut = cur;                       // dead value on the last 2 iters
        if (k + 2 < ITERS)                   // compile-time (fully unrolled)
            fut = __builtin_nontemporal_load(xv + idx + 2 * stride);

        // pass 1: speculative 4 steps from (0,0)  (valid for even lanes)
        float u = 0.0f, o = 0.0f;
#pragma unroll
        for (int t = 0; t < 4; ++t) {
            u = LIF_TAU * u * (1.0f - o) + cur[t];
            o = (u > LIF_VTH) ? 1.0f : 0.0f;
        }

        // carry exchange with pair partner (adjacent lane, same wave)
        float cu = __shfl_xor(u, 1);
        float co = __shfl_xor(o, 1);
        u = odd ? cu : 0.0f;
        o = odd ? co : 0.0f;

        // pass 2: definitive 4 steps, emit spikes
        v4f w;
#pragma unroll
        for (int t = 0; t < 4; ++t) {
            u = LIF_TAU * u * (1.0f - o) + cur[t];
            o = (u > LIF_VTH) ? 1.0f : 0.0f;
            w[t] = o;
        }
        __builtin_nontemporal_store(w, ov + idx);

        cur = nxt;
        nxt = fut;
        idx += stride;
    }
}

extern "C" void kernel_launch(void* const* d_in, const int* in_sizes, int n_in,
                              void* d_out, int out_size, void* d_ws, size_t ws_size,
                              hipStream_t stream) {
    const float* x = (const float*)d_in[0];
    float* out = (float*)d_out;
    int n_elems = in_sizes[0];                 // 33,554,432
    int n_vec4 = n_elems / 4;                  // 8,388,608 float4s
    int n_blocks = n_vec4 / (BLOCK * ITERS);   // 2,048 blocks -> 8 wg/CU resident

    lif_spike_kernel<<<n_blocks, BLOCK, 0, stream>>>(x, out);
}

// Round 3
// 217.857 us; speedup vs baseline: 1.0248x; 1.0248x over previous
//
#include <hip/hip_runtime.h>

// LIF recurrence over last (time) dim, T=8, fp32 in/out. 4,194,304 neurons.
//   u_t = TAU * u_{t-1} * (1 - o_{t-1}) + x_t ;  o_t = (u_t > VTH) ? 1 : 0
//
// Memory-bound: 134 MB read + 134 MB write -> ~43 us floor at ~6.3 TB/s.
// Unit-stride float4 load/store per lane; a neuron's two time-halves live in
// adjacent lanes (pair 2n/2n+1 of the same wave), so the recurrence carry is
// exchanged in-register via __shfl_xor(1) -- no LDS, no barriers.
//   pass 1: all lanes run their 4 steps from (u,o)=(0,0)   (valid for even lanes)
//   xchg  : odd lanes take partner's (u,o) as carry; even lanes take (0,0)
//   pass 2: all lanes re-run their 4 steps with the correct carry and emit spikes
//
// Schedule: one float4 per thread, 32768 launch-and-die blocks -- measured
// best of {1-chunk/32K blk, 4-chunk/8K blk, 16-chunk persistent pipelined}
// (215.7 / 218.8 / 223.3 us headline). This revision: drop the nontemporal
// hints. x (134 MB) fits in the 256 MB Infinity Cache and is never poisoned
// by the harness reset; cached loads let repeat iterations hit L3 instead of
// forcing HBM reads, and cached stores complete at L2 with writeback
// overlapping the subsequent restore dispatches.

#define LIF_TAU 0.25f
#define LIF_VTH 0.3f
#define BLOCK 256

typedef float v4f __attribute__((ext_vector_type(4)));

__global__ __launch_bounds__(BLOCK) void lif_spike_kernel(
    const float* __restrict__ x, float* __restrict__ out) {
    const size_t g = (size_t)blockIdx.x * BLOCK + threadIdx.x;

    const v4f* __restrict__ xv = reinterpret_cast<const v4f*>(x);
    v4f* __restrict__ ov = reinterpret_cast<v4f*>(out);

    v4f v = xv[g];   // cached load: floats [4g .. 4g+3]

    // pass 1: speculative 4 steps from (0,0)
    float u = 0.0f, o = 0.0f;
#pragma unroll
    for (int k = 0; k < 4; ++k) {
        u = LIF_TAU * u * (1.0f - o) + v[k];
        o = (u > LIF_VTH) ? 1.0f : 0.0f;
    }

    // carry exchange with pair partner (adjacent lane, same wave)
    float cu = __shfl_xor(u, 1);
    float co = __shfl_xor(o, 1);
    const bool odd = (threadIdx.x & 1) != 0;
    u = odd ? cu : 0.0f;
    o = odd ? co : 0.0f;

    // pass 2: definitive 4 steps (even lanes recompute identical values)
    v4f w;
#pragma unroll
    for (int k = 0; k < 4; ++k) {
        u = LIF_TAU * u * (1.0f - o) + v[k];
        o = (u > LIF_VTH) ? 1.0f : 0.0f;
        w[k] = o;
    }

    ov[g] = w;       // cached store: completes at L2, writeback overlaps
}

extern "C" void kernel_launch(void* const* d_in, const int* in_sizes, int n_in,
                              void* d_out, int out_size, void* d_ws, size_t ws_size,
                              hipStream_t stream) {
    const float* x = (const float*)d_in[0];
    float* out = (float*)d_out;
    int n_elems = in_sizes[0];        // 33,554,432
    int n_vec4 = n_elems / 4;         // 8,388,608 float4s, one per thread
    int n_blocks = n_vec4 / BLOCK;    // 32768

    lif_spike_kernel<<<n_blocks, BLOCK, 0, stream>>>(x, out);
}

// Round 4
// 215.071 us; speedup vs baseline: 1.0381x; 1.0130x over previous
//
#include <hip/hip_runtime.h>

// LIF recurrence over last (time) dim, T=8, fp32 in/out. 4,194,304 neurons.
//   u_t = TAU * u_{t-1} * (1 - o_{t-1}) + x_t ;  o_t = (u_t > VTH) ? 1 : 0
//
// Memory-bound: 134 MB read + 134 MB write -> ~43 us floor at ~6.3 TB/s.
// Unit-stride float4 load/store per lane; the neuron's two time-halves live
// in adjacent lanes (pair 2n/2n+1 of the same wave), so the recurrence carry
// is exchanged in-register via __shfl_xor(1) -- no LDS, no barriers.
//   pass 1: all lanes run their 4 steps from (u,o)=(0,0)   (valid for even lanes)
//   xchg  : odd lanes take partner's (u,o) as carry; even lanes take (0,0)
//   pass 2: all lanes re-run their 4 steps with the correct carry and emit spikes
//
// Tuning ledger (headline us; fills ~160 us of it are harness resets):
//   nt, 1 float4/thread, 32768 blocks   : 215.7   <- BEST (this version)
//   nt, 4 chunks/thread,  8192 blocks   : 218.8   (ILP batching: no gain)
//   nt, persistent 16-chunk pipelined   : 223.3   (grid-stride: regression)
//   cached, 1 float4/thread             : 217.9   (x can't survive the 1 GB
//                                                  poison-fill sweep; nt store
//                                                  avoids L2 write-allocate)
// Kernel dispatch itself is < 80 us (never in rocprof top-5), vs a 42.6 us
// copy-roofline for its irreducible 268 MB of perfectly-coalesced traffic.

#define LIF_TAU 0.25f
#define LIF_VTH 0.3f
#define BLOCK 256

typedef float v4f __attribute__((ext_vector_type(4)));

__global__ __launch_bounds__(BLOCK) void lif_spike_kernel(
    const float* __restrict__ x, float* __restrict__ out) {
    const size_t g = (size_t)blockIdx.x * BLOCK + threadIdx.x;

    const v4f* __restrict__ xv = reinterpret_cast<const v4f*>(x);
    v4f* __restrict__ ov = reinterpret_cast<v4f*>(out);

    v4f v = __builtin_nontemporal_load(xv + g);   // floats [4g .. 4g+3]

    // pass 1: speculative 4 steps from (0,0)
    float u = 0.0f, o = 0.0f;
#pragma unroll
    for (int k = 0; k < 4; ++k) {
        u = LIF_TAU * u * (1.0f - o) + v[k];
        o = (u > LIF_VTH) ? 1.0f : 0.0f;
    }

    // carry exchange with pair partner (adjacent lane, same wave)
    float cu = __shfl_xor(u, 1);
    float co = __shfl_xor(o, 1);
    const bool odd = (threadIdx.x & 1) != 0;
    u = odd ? cu : 0.0f;
    o = odd ? co : 0.0f;

    // pass 2: definitive 4 steps (even lanes recompute identical values)
    v4f w;
#pragma unroll
    for (int k = 0; k < 4; ++k) {
        u = LIF_TAU * u * (1.0f - o) + v[k];
        o = (u > LIF_VTH) ? 1.0f : 0.0f;
        w[k] = o;
    }

    __builtin_nontemporal_store(w, ov + g);
}

extern "C" void kernel_launch(void* const* d_in, const int* in_sizes, int n_in,
                              void* d_out, int out_size, void* d_ws, size_t ws_size,
                              hipStream_t stream) {
    const float* x = (const float*)d_in[0];
    float* out = (float*)d_out;
    int n_elems = in_sizes[0];        // 33,554,432
    int n_vec4 = n_elems / 4;         // 8,388,608 float4s, one per thread
    int n_blocks = n_vec4 / BLOCK;    // 32768

    lif_spike_kernel<<<n_blocks, BLOCK, 0, stream>>>(x, out);
}